// Round 1
// baseline (826.782 us; speedup 1.0000x reference)
//
#include <hip/hip_runtime.h>
#include <cstdint>
#include <cstddef>

#define NB 8
#define NC 128
#define NHH 160
#define NWW 160
#define NNN (NHH*NWW)        // 25600
#define TILE_R 64
#define TPB (NNN/TILE_R)     // 400 tiles per batch
#define NSLOTS 32
#define LDSP 132             // padded LDS row stride (floats)

__device__ __forceinline__ float elup1(float y) {
  // elu(y)+1 : y>0 -> y+1 ; else exp(y)
  return y > 0.f ? y + 1.f : __expf(y);
}

// ---------------------------------------------------------------------------
// K1: projection GEMM (q,k), q -> ws, k -> rope -> kv/ksum partial reductions
// ---------------------------------------------------------------------------
__global__ __launch_bounds__(256) void k1_proj(
    const float* __restrict__ x, const float* __restrict__ qk_w,
    const float* __restrict__ qk_b, float* __restrict__ qout,
    float* __restrict__ kv_part, float* __restrict__ ksum_part)
{
  __shared__ float xs[TILE_R][LDSP];   // x tile (v operand too)
  __shared__ float wch[64][LDSP];      // weight chunk; reused as roped-k tile
  __shared__ float ksum_lds[NC];

  const int blk  = blockIdx.x;
  const int b    = blk / TPB;
  const int tile = blk - b * TPB;
  const int i0   = tile * TILE_R;
  const int tid  = threadIdx.x;
  const float* xb = x + (size_t)b * NNN * NC;

  { // stage x tile: 64*128 contiguous floats
    const float4* src = (const float4*)(xb + (size_t)i0 * NC);
    for (int f = tid; f < TILE_R*NC/4; f += 256) {
      float4 v = src[f];
      *(float4*)&xs[f >> 5][(f & 31) << 2] = v;
    }
  }
  if (tid < NC) ksum_lds[tid] = 0.f;

  const int rg = tid >> 4, cg = tid & 15;
  const int r0 = rg << 2;

  float kvacc[8];
  #pragma unroll
  for (int t = 0; t < 8; ++t) kvacc[t] = 0.f;

  for (int chunk = 0; chunk < 4; ++chunk) {
    __syncthreads();  // protect wch (weights or roped-k) from prior readers
    { // stage weight chunk: qk_w rows [chunk*64, chunk*64+64)
      const float4* wsrc = (const float4*)(qk_w + (size_t)chunk * 64 * NC);
      for (int f = tid; f < 64*NC/4; f += 256) {
        float4 v = wsrc[f];
        *(float4*)&wch[f >> 5][(f & 31) << 2] = v;
      }
    }
    __syncthreads();

    float acc[4][4];
    #pragma unroll
    for (int ii = 0; ii < 4; ++ii)
      #pragma unroll
      for (int jj = 0; jj < 4; ++jj) acc[ii][jj] = 0.f;

    #pragma unroll 8
    for (int kk = 0; kk < NC; kk += 4) {
      float4 a0 = *(const float4*)&xs[r0+0][kk];
      float4 a1 = *(const float4*)&xs[r0+1][kk];
      float4 a2 = *(const float4*)&xs[r0+2][kk];
      float4 a3 = *(const float4*)&xs[r0+3][kk];
      float4 w0 = *(const float4*)&wch[(cg<<2)+0][kk];
      float4 w1 = *(const float4*)&wch[(cg<<2)+1][kk];
      float4 w2 = *(const float4*)&wch[(cg<<2)+2][kk];
      float4 w3 = *(const float4*)&wch[(cg<<2)+3][kk];
      acc[0][0] += a0.x*w0.x + a0.y*w0.y + a0.z*w0.z + a0.w*w0.w;
      acc[0][1] += a0.x*w1.x + a0.y*w1.y + a0.z*w1.z + a0.w*w1.w;
      acc[0][2] += a0.x*w2.x + a0.y*w2.y + a0.z*w2.z + a0.w*w2.w;
      acc[0][3] += a0.x*w3.x + a0.y*w3.y + a0.z*w3.z + a0.w*w3.w;
      acc[1][0] += a1.x*w0.x + a1.y*w0.y + a1.z*w0.z + a1.w*w0.w;
      acc[1][1] += a1.x*w1.x + a1.y*w1.y + a1.z*w1.z + a1.w*w1.w;
      acc[1][2] += a1.x*w2.x + a1.y*w2.y + a1.z*w2.z + a1.w*w2.w;
      acc[1][3] += a1.x*w3.x + a1.y*w3.y + a1.z*w3.z + a1.w*w3.w;
      acc[2][0] += a2.x*w0.x + a2.y*w0.y + a2.z*w0.z + a2.w*w0.w;
      acc[2][1] += a2.x*w1.x + a2.y*w1.y + a2.z*w1.z + a2.w*w1.w;
      acc[2][2] += a2.x*w2.x + a2.y*w2.y + a2.z*w2.z + a2.w*w2.w;
      acc[2][3] += a2.x*w3.x + a2.y*w3.y + a2.z*w3.z + a2.w*w3.w;
      acc[3][0] += a3.x*w0.x + a3.y*w0.y + a3.z*w0.z + a3.w*w0.w;
      acc[3][1] += a3.x*w1.x + a3.y*w1.y + a3.z*w1.z + a3.w*w1.w;
      acc[3][2] += a3.x*w2.x + a3.y*w2.y + a3.z*w2.z + a3.w*w2.w;
      acc[3][3] += a3.x*w3.x + a3.y*w3.y + a3.z*w3.z + a3.w*w3.w;
    }

    const int cbase = (chunk << 6) + (cg << 2);
    const float b0 = qk_b[cbase+0], b1 = qk_b[cbase+1];
    const float b2 = qk_b[cbase+2], b3 = qk_b[cbase+3];

    if (chunk < 2) {
      // q chunk: activation + store (non-roped; K2 applies rope)
      #pragma unroll
      for (int ii = 0; ii < 4; ++ii) {
        float4 qv;
        qv.x = elup1(acc[ii][0] + b0);
        qv.y = elup1(acc[ii][1] + b1);
        qv.z = elup1(acc[ii][2] + b2);
        qv.w = elup1(acc[ii][3] + b3);
        *(float4*)(qout + ((size_t)b*NNN + (size_t)(i0 + r0 + ii))*NC + cbase) = qv;
      }
    } else {
      // k chunk: activation, ksum, rope, then kv partial accumulation
      const int d0 = cbase - NC;               // k channel base 0..127
      const float th0 = __expf(-0.14391157f * (float)(d0 >> 1));
      const float th1 = __expf(-0.14391157f * (float)((d0 >> 1) + 1));
      float4 krr[4];
      float ks0 = 0.f, ks1 = 0.f, ks2 = 0.f, ks3 = 0.f;
      #pragma unroll
      for (int ii = 0; ii < 4; ++ii) {
        float v0 = elup1(acc[ii][0] + b0);
        float v1 = elup1(acc[ii][1] + b1);
        float v2 = elup1(acc[ii][2] + b2);
        float v3 = elup1(acc[ii][3] + b3);
        ks0 += v0; ks1 += v1; ks2 += v2; ks3 += v3;
        const float wf = (float)((i0 + r0 + ii) % NWW);   // rope angle uses w coord
        float s0, c0, s1, c1;
        __sincosf(wf*th0, &s0, &c0);
        __sincosf(wf*th1, &s1, &c1);
        krr[ii].x = v0*c0 - v1*s0;
        krr[ii].y = v0*s0 + v1*c0;
        krr[ii].z = v2*c1 - v3*s1;
        krr[ii].w = v2*s1 + v3*c1;
      }
      atomicAdd(&ksum_lds[d0+0], ks0);
      atomicAdd(&ksum_lds[d0+1], ks1);
      atomicAdd(&ksum_lds[d0+2], ks2);
      atomicAdd(&ksum_lds[d0+3], ks3);
      __syncthreads();                 // all GEMM reads of wch done
      #pragma unroll
      for (int ii = 0; ii < 4; ++ii)   // store roped k into wch (cols 0..63)
        *(float4*)&wch[r0+ii][cg<<2] = krr[ii];
      __syncthreads();                 // roped-k tile ready

      const int half = chunk - 2;
      const int hloc = tid >> 6;           // 0..3  (wave-uniform)
      const int dd   = (tid >> 2) & 15;
      const int e0   = (tid & 3) << 2;
      const int kcol = (hloc << 4) + dd;                 // within 0..63
      const int vcol = (((half << 2) + hloc) << 4) + e0; // v channel base
      float a0 = kvacc[half*4+0], a1 = kvacc[half*4+1];
      float a2 = kvacc[half*4+2], a3 = kvacc[half*4+3];
      #pragma unroll 8
      for (int r = 0; r < TILE_R; ++r) {
        float  kr = wch[r][kcol];
        float4 vv = *(const float4*)&xs[r][vcol];
        a0 += kr*vv.x; a1 += kr*vv.y; a2 += kr*vv.z; a3 += kr*vv.w;
      }
      kvacc[half*4+0] = a0; kvacc[half*4+1] = a1;
      kvacc[half*4+2] = a2; kvacc[half*4+3] = a3;
    }
  }

  // write partials (slot-sliced atomics; ~12 contenders per address)
  const int slot = blk & (NSLOTS-1);
  float* kvp = kv_part + ((size_t)b*NSLOTS + slot) * 2048;
  #pragma unroll
  for (int half = 0; half < 2; ++half) {
    #pragma unroll
    for (int j = 0; j < 4; ++j)
      atomicAdd(&kvp[half*1024 + tid*4 + j], kvacc[half*4+j]);
  }
  __syncthreads();
  if (tid < NC) atomicAdd(&ksum_part[((size_t)b*NSLOTS + slot)*NC + tid], ksum_lds[tid]);
}

// ---------------------------------------------------------------------------
// Kred: reduce slots -> kv (scaled 1/n) and kmean
// ---------------------------------------------------------------------------
__global__ __launch_bounds__(256) void k_reduce(
    const float* __restrict__ kv_part, const float* __restrict__ ksum_part,
    float* __restrict__ kvf, float* __restrict__ kmean)
{
  const int gtid = blockIdx.x * 256 + threadIdx.x;   // 0..16383
  const int b = gtid >> 11;
  const int cidx = gtid & 2047;
  float s = 0.f;
  for (int sl = 0; sl < NSLOTS; ++sl)
    s += kv_part[((size_t)b*NSLOTS + sl)*2048 + cidx];
  kvf[(size_t)b*2048 + cidx] = s * (1.f/25600.f);
  if (cidx < NC) {
    float t = 0.f;
    for (int sl = 0; sl < NSLOTS; ++sl)
      t += ksum_part[((size_t)b*NSLOTS + sl)*NC + cidx];
    kmean[(size_t)b*NC + cidx] = t * (1.f/25600.f);
  }
}

// ---------------------------------------------------------------------------
// K2: rope(q), z, attn-out vs kv, fused LePE, transposed coalesced store
// ---------------------------------------------------------------------------
__global__ __launch_bounds__(256) void k2_out(
    const float* __restrict__ x, const float* __restrict__ qbuf,
    const float* __restrict__ kvf, const float* __restrict__ kmean,
    const float* __restrict__ lepe_w, const float* __restrict__ lepe_b,
    float* __restrict__ outp)
{
  __shared__ float kv_s[2048];
  __shared__ float km_s[NC];
  __shared__ float ot[TILE_R][NC];

  const int blk  = blockIdx.x;
  const int b    = blk / TPB;
  const int tile = blk - b * TPB;
  const int i0   = tile * TILE_R;
  const int tid  = threadIdx.x;
  const int ch   = tid & (NC-1);
  const int rh   = tid >> 7;          // 0..1: two rows per iteration

  for (int f = tid; f < 2048; f += 256) kv_s[f] = kvf[(size_t)b*2048 + f];
  if (tid < NC) km_s[tid] = kmean[(size_t)b*NC + tid];

  const int h  = ch >> 4;
  const int cl = ch & 15;
  const float theta = __expf(-0.14391157f * (float)(ch >> 1));
  float wl[9];
  #pragma unroll
  for (int t = 0; t < 9; ++t) wl[t] = lepe_w[ch*9 + t];
  const float lb = lepe_b[ch];
  const float* xb = x    + (size_t)b*NNN*NC;
  const float* qb = qbuf + (size_t)b*NNN*NC;
  __syncthreads();

  for (int rr = 0; rr < TILE_R; rr += 2) {
    const int i = i0 + rr + rh;
    const float qv = qb[(size_t)i*NC + ch];
    const float qp = __shfl_xor(qv, 1);       // rope pair partner (adjacent lane)
    const int hh  = i / NWW;
    const int www = i - hh * NWW;
    float s, c;
    __sincosf((float)www * theta, &s, &c);
    const float qr = (ch & 1) ? (qp*s + qv*c) : (qv*c - qp*s);
    // z = 1/(dot(q_head, kmean_head) + 1e-6): 16-lane shuffle reduce
    float zp = qv * km_s[ch];
    zp += __shfl_xor(zp, 1);
    zp += __shfl_xor(zp, 2);
    zp += __shfl_xor(zp, 4);
    zp += __shfl_xor(zp, 8);
    const float z = 1.f / (zp + 1e-6f);
    // attn out: sum_d qr[h*16+d] * kv[h][d][cl]
    float acc = 0.f;
    #pragma unroll
    for (int d = 0; d < 16; ++d) {
      float qd = __shfl(qr, d, 16);
      acc += qd * kv_s[(h << 8) + (d << 4) + cl];
    }
    acc *= z;
    // LePE 3x3 depthwise (zero pad)
    float lp = lb;
    #pragma unroll
    for (int dy = -1; dy <= 1; ++dy) {
      const int h2 = hh + dy;
      if (h2 < 0 || h2 >= NHH) continue;
      #pragma unroll
      for (int dx = -1; dx <= 1; ++dx) {
        const int w2 = www + dx;
        if (w2 < 0 || w2 >= NWW) continue;
        lp += wl[(dy+1)*3 + (dx+1)] * xb[((size_t)(h2*NWW + w2))*NC + ch];
      }
    }
    ot[rr + rh][ch] = acc + lp;
  }
  __syncthreads();
  // transposed write-out: contiguous runs along i per channel
  const int ch2 = tid >> 1;
  const int ihalf = tid & 1;
  float* ob = outp + ((size_t)b*NC + ch2)*NNN + i0 + ihalf*32;
  #pragma unroll
  for (int rr4 = 0; rr4 < 32; rr4 += 4) {
    const int rbase = ihalf*32 + rr4;
    float4 v = make_float4(ot[rbase+0][ch2], ot[rbase+1][ch2],
                           ot[rbase+2][ch2], ot[rbase+3][ch2]);
    *(float4*)(ob + rr4) = v;
  }
}

// ---------------------------------------------------------------------------
extern "C" void kernel_launch(void* const* d_in, const int* in_sizes, int n_in,
                              void* d_out, int out_size, void* d_ws, size_t ws_size,
                              hipStream_t stream) {
  const float* x      = (const float*)d_in[0];
  const float* qk_w   = (const float*)d_in[1];
  const float* qk_b   = (const float*)d_in[2];
  const float* lepe_w = (const float*)d_in[3];
  const float* lepe_b = (const float*)d_in[4];
  float* outp = (float*)d_out;

  float* ws        = (float*)d_ws;
  float* qbuf      = ws;                                        // B*N*C
  float* kv_part   = qbuf + (size_t)NB*NNN*NC;                  // B*NSLOTS*2048
  float* ksum_part = kv_part + (size_t)NB*NSLOTS*2048;          // B*NSLOTS*NC
  float* kvf       = ksum_part + (size_t)NB*NSLOTS*NC;          // B*2048
  float* kmean     = kvf + (size_t)NB*2048;                     // B*NC

  // zero partial-accumulator region every launch (ws poisoned once by harness)
  (void)hipMemsetAsync(kv_part, 0,
      ((size_t)NB*NSLOTS*2048 + (size_t)NB*NSLOTS*NC) * sizeof(float), stream);

  hipLaunchKernelGGL(k1_proj, dim3(NB*TPB), dim3(256), 0, stream,
                     x, qk_w, qk_b, qbuf, kv_part, ksum_part);
  hipLaunchKernelGGL(k_reduce, dim3(64), dim3(256), 0, stream,
                     kv_part, ksum_part, kvf, kmean);
  hipLaunchKernelGGL(k2_out, dim3(NB*TPB), dim3(256), 0, stream,
                     x, qbuf, kvf, kmean, lepe_w, lepe_b, outp);
}

// Round 2
// 696.417 us; speedup vs baseline: 1.1872x; 1.1872x over previous
//
#include <hip/hip_runtime.h>
#include <cstdint>
#include <cstddef>

#define NB 8
#define NC 128
#define NHH 160
#define NWW 160
#define NNN (NHH*NWW)        // 25600
#define TILE_R 64
#define TPB (NNN/TILE_R)     // 400 tiles per batch
#define NSLOTS 32
#define LN_BASE_OVER_KMAX 0.14391156511f   // ln(10000)/64

typedef __attribute__((ext_vector_type(8))) short short8v;
typedef __attribute__((ext_vector_type(4))) short short4v;
typedef __attribute__((ext_vector_type(4))) float f32x4;

union B64x2 { short8v v8; short4v v4[2]; };

__device__ __forceinline__ float elup1(float y) {
  return y > 0.f ? y + 1.f : __expf(y);
}
__device__ __forceinline__ ushort f2bf(float f) {
  uint x = __float_as_uint(f);
  x += 0x7fffu + ((x >> 16) & 1u);
  return (ushort)(x >> 16);
}
__device__ __forceinline__ float bf2f(ushort u) {
  return __uint_as_float(((uint)u) << 16);
}

// ---------------------------------------------------------------------------
// K1: MFMA projection GEMM (q,k); q->bf16 ws; k->rope->kv (MFMA) + ksum
// ---------------------------------------------------------------------------
__global__ __launch_bounds__(256) void k1_proj(
    const float* __restrict__ x, const float* __restrict__ qk_w,
    const float* __restrict__ qk_b, ushort* __restrict__ qout,
    float* __restrict__ kv_part, float* __restrict__ ksum_part)
{
  __shared__ __align__(16) ushort xbf[64][136];   // x tile bf16, row-major
  __shared__ __align__(16) ushort wch[64][136];   // W chunk bf16
  __shared__ __align__(16) ushort xtp[128][68];   // x tile bf16, transposed [ch][row]
  __shared__ __align__(16) ushort krt[128][68];   // roped k bf16, transposed [kc][row]
  __shared__ float ksum_lds[NC];

  const int blk  = blockIdx.x;
  const int b    = blk / TPB;
  const int tile = blk - b * TPB;
  const int i0   = tile * TILE_R;
  const int tid  = threadIdx.x;
  const int lane = tid & 63;
  const int wv   = tid >> 6;        // wave 0..3
  const int lg   = lane >> 4;       // 0..3
  const int ll   = lane & 15;
  const float* xb = x + (size_t)b*NNN*NC + (size_t)i0*NC;

  // stage xbf (row-major) — coalesced float4 reads
  {
    const float4* src = (const float4*)xb;
    for (int f = tid; f < TILE_R*NC/4; f += 256) {
      float4 v = src[f];
      ushort4 u = make_ushort4(f2bf(v.x), f2bf(v.y), f2bf(v.z), f2bf(v.w));
      *(ushort4*)&xbf[f >> 5][(f & 31) << 2] = u;
    }
  }
  // stage xtp (transposed) — column gathers (L1/L2-hot re-read)
  for (int f = tid; f < 2048; f += 256) {
    const int c = f & 127, rg = f >> 7;       // rows rg*4 .. rg*4+3
    float v0 = xb[(size_t)(rg*4+0)*NC + c];
    float v1 = xb[(size_t)(rg*4+1)*NC + c];
    float v2 = xb[(size_t)(rg*4+2)*NC + c];
    float v3 = xb[(size_t)(rg*4+3)*NC + c];
    ushort4 u = make_ushort4(f2bf(v0), f2bf(v1), f2bf(v2), f2bf(v3));
    *(ushort4*)&xtp[c][rg*4] = u;
  }
  if (tid < NC) ksum_lds[tid] = 0.f;

  f32x4 kvacc[2];
  kvacc[0] = (f32x4){0.f,0.f,0.f,0.f};
  kvacc[1] = (f32x4){0.f,0.f,0.f,0.f};
  const int slot = blk & (NSLOTS-1);

  for (int chunk = 0; chunk < 4; ++chunk) {
    __syncthreads();   // prior readers of wch done (iter0: xbf/xtp writes ordered)
    { // stage W chunk rows [chunk*64, +64) as bf16
      const float4* wsrc = (const float4*)(qk_w + (size_t)chunk*64*NC);
      for (int f = tid; f < 64*NC/4; f += 256) {
        float4 v = wsrc[f];
        ushort4 u = make_ushort4(f2bf(v.x), f2bf(v.y), f2bf(v.z), f2bf(v.w));
        *(ushort4*)&wch[f >> 5][(f & 31) << 2] = u;
      }
    }
    __syncthreads();

    // GEMM: wave wv owns m-tile wv (rows 16wv..16wv+15), 4 n-tiles, K=128
    f32x4 acc[4];
    acc[0]=acc[1]=acc[2]=acc[3]=(f32x4){0.f,0.f,0.f,0.f};
    #pragma unroll
    for (int ks = 0; ks < 4; ++ks) {
      short8v a = *(const short8v*)&xbf[(wv<<4) + ll][(ks<<5) + (lg<<3)];
      #pragma unroll
      for (int nt = 0; nt < 4; ++nt) {
        short8v bb = *(const short8v*)&wch[(nt<<4) + ll][(ks<<5) + (lg<<3)];
        acc[nt] = __builtin_amdgcn_mfma_f32_16x16x32_bf16(a, bb, acc[nt], 0, 0, 0);
      }
    }

    const int row0 = (wv<<4) + (lg<<2);   // local row base in C/D layout
    if (chunk < 2) {
      // q epilogue: bias + elu+1 -> bf16 store
      #pragma unroll
      for (int nt = 0; nt < 4; ++nt) {
        const int cg = (chunk<<6) + (nt<<4) + ll;
        const float bias = qk_b[cg];
        #pragma unroll
        for (int r = 0; r < 4; ++r) {
          float v = elup1(acc[nt][r] + bias);
          qout[((size_t)b*NNN + (size_t)(i0 + row0 + r))*NC + cg] = f2bf(v);
        }
      }
    } else {
      // k epilogue: bias + elu+1, ksum, rope, transposed bf16 store
      #pragma unroll
      for (int nt = 0; nt < 4; ++nt) {
        const int kc = ((chunk-2)<<6) + (nt<<4) + ll;
        const float bias = qk_b[NC + kc];
        float kk[4]; float ss = 0.f;
        #pragma unroll
        for (int r = 0; r < 4; ++r) { kk[r] = elup1(acc[nt][r] + bias); ss += kk[r]; }
        atomicAdd(&ksum_lds[kc], ss);
        const float theta = __expf(-LN_BASE_OVER_KMAX * (float)(kc >> 1));
        ushort rb[4];
        #pragma unroll
        for (int r = 0; r < 4; ++r) {
          float p = __shfl_xor(kk[r], 1);     // pair partner (adjacent lane)
          const int i = i0 + row0 + r;
          const float wf = (float)(i - (i/NWW)*NWW);
          float s, c; __sincosf(wf*theta, &s, &c);
          float kr = (kc & 1) ? (p*s + kk[r]*c) : (kk[r]*c - p*s);
          rb[r] = f2bf(kr);
        }
        *(uint*)&krt[kc][row0]   = (uint)rb[0] | ((uint)rb[1] << 16);
        *(uint*)&krt[kc][row0+2] = (uint)rb[2] | ((uint)rb[3] << 16);
      }
      __syncthreads();   // krt tile ready (xtp ready since earlier barriers)
      // kv via MFMA: head h, kv_h(16x16) += krt_h^T-slices . v_h over 64 rows
      const int h  = ((chunk-2)<<2) + wv;
      const int e2 = chunk - 2;
      #pragma unroll
      for (int ks = 0; ks < 2; ++ks) {
        const int rb2 = (ks<<5) + (lg<<3);
        B64x2 ua, ub;
        ua.v4[0] = *(const short4v*)&krt[(h<<4) + ll][rb2];
        ua.v4[1] = *(const short4v*)&krt[(h<<4) + ll][rb2+4];
        ub.v4[0] = *(const short4v*)&xtp[(h<<4) + ll][rb2];
        ub.v4[1] = *(const short4v*)&xtp[(h<<4) + ll][rb2+4];
        kvacc[e2] = __builtin_amdgcn_mfma_f32_16x16x32_bf16(ua.v8, ub.v8, kvacc[e2], 0, 0, 0);
      }
    }
  }

  // kv partial atomics: lane holds kv_h[d=(lg*4+r)][e=ll]
  {
    float* kvp = kv_part + ((size_t)b*NSLOTS + slot) * 2048;
    #pragma unroll
    for (int e2 = 0; e2 < 2; ++e2) {
      const int h = (e2<<2) + wv;
      #pragma unroll
      for (int r = 0; r < 4; ++r) {
        const int d = (lg<<2) + r;
        atomicAdd(&kvp[(h<<8) + (d<<4) + ll], kvacc[e2][r]);
      }
    }
  }
  __syncthreads();
  if (tid < NC) atomicAdd(&ksum_part[((size_t)b*NSLOTS + slot)*NC + tid], ksum_lds[tid]);
}

// ---------------------------------------------------------------------------
// Kred: reduce slots -> kv (scaled 1/n) and kmean
// ---------------------------------------------------------------------------
__global__ __launch_bounds__(256) void k_reduce(
    const float* __restrict__ kv_part, const float* __restrict__ ksum_part,
    float* __restrict__ kvf, float* __restrict__ kmean)
{
  const int gtid = blockIdx.x * 256 + threadIdx.x;   // 0..16383
  const int b = gtid >> 11;
  const int cidx = gtid & 2047;
  float s = 0.f;
  for (int sl = 0; sl < NSLOTS; ++sl)
    s += kv_part[((size_t)b*NSLOTS + sl)*2048 + cidx];
  kvf[(size_t)b*2048 + cidx] = s * (1.f/25600.f);
  if (cidx < NC) {
    float t = 0.f;
    for (int sl = 0; sl < NSLOTS; ++sl)
      t += ksum_part[((size_t)b*NSLOTS + sl)*NC + cidx];
    kmean[(size_t)b*NC + cidx] = t * (1.f/25600.f);
  }
}

// ---------------------------------------------------------------------------
// K2: cooperative rope(q)+z phase, shuffle-free attn (reg kv, broadcast qr),
//     fused LePE, transposed coalesced store
// ---------------------------------------------------------------------------
__global__ __launch_bounds__(256) void k2_out(
    const float* __restrict__ x, const ushort* __restrict__ qbuf,
    const float* __restrict__ kvf, const float* __restrict__ kmean,
    const float* __restrict__ lepe_w, const float* __restrict__ lepe_b,
    float* __restrict__ outp)
{
  __shared__ __align__(16) float qr_s[64][160];  // head stride 20 -> conflict-free b128
  __shared__ float ot[64][132];
  __shared__ float z_s[64][8];
  __shared__ float km_s[NC];

  const int blk  = blockIdx.x;
  const int b    = blk / TPB;
  const int tile = blk - b * TPB;
  const int i0   = tile * TILE_R;
  const int tid  = threadIdx.x;

  if (tid < NC) km_s[tid] = kmean[(size_t)b*NC + tid];

  const int ch = tid & (NC-1);
  const int rh = tid >> 7;
  const int h  = ch >> 4;
  const int cl = ch & 15;
  float kvreg[16];
  #pragma unroll
  for (int d = 0; d < 16; ++d)
    kvreg[d] = kvf[(size_t)b*2048 + (h<<8) + (d<<4) + cl];
  float wl[9];
  #pragma unroll
  for (int t = 0; t < 9; ++t) wl[t] = lepe_w[ch*9 + t];
  const float lb = lepe_b[ch];
  const float* xb = x + (size_t)b*NNN*NC;
  __syncthreads();   // km_s ready

  // phase B: rope + z, one (row,head) per task, 2 tasks/thread
  #pragma unroll
  for (int t2 = 0; t2 < 2; ++t2) {
    const int id  = tid + (t2 << 8);
    const int row = id >> 3;
    const int hd  = id & 7;
    const ushort* qp = qbuf + ((size_t)b*NNN + (size_t)(i0 + row))*NC + (hd<<4);
    uint4 u0 = *(const uint4*)qp;
    uint4 u1 = *(const uint4*)(qp + 8);
    float q[16];
    q[0] = bf2f((ushort)(u0.x & 0xffff)); q[1] = bf2f((ushort)(u0.x >> 16));
    q[2] = bf2f((ushort)(u0.y & 0xffff)); q[3] = bf2f((ushort)(u0.y >> 16));
    q[4] = bf2f((ushort)(u0.z & 0xffff)); q[5] = bf2f((ushort)(u0.z >> 16));
    q[6] = bf2f((ushort)(u0.w & 0xffff)); q[7] = bf2f((ushort)(u0.w >> 16));
    q[8] = bf2f((ushort)(u1.x & 0xffff)); q[9] = bf2f((ushort)(u1.x >> 16));
    q[10]= bf2f((ushort)(u1.y & 0xffff)); q[11]= bf2f((ushort)(u1.y >> 16));
    q[12]= bf2f((ushort)(u1.z & 0xffff)); q[13]= bf2f((ushort)(u1.z >> 16));
    q[14]= bf2f((ushort)(u1.w & 0xffff)); q[15]= bf2f((ushort)(u1.w >> 16));
    float zp = 0.f;
    #pragma unroll
    for (int j = 0; j < 16; ++j) zp += q[j] * km_s[(hd<<4) + j];
    z_s[row][hd] = 1.f / (zp + 1e-6f);
    const int i = i0 + row;
    const float wf = (float)(i - (i/NWW)*NWW);
    float qr[16];
    #pragma unroll
    for (int j = 0; j < 8; ++j) {
      float th = __expf(-LN_BASE_OVER_KMAX * (float)((hd<<3) + j));
      float s, c; __sincosf(wf*th, &s, &c);
      qr[2*j]   = q[2*j]*c - q[2*j+1]*s;
      qr[2*j+1] = q[2*j]*s + q[2*j+1]*c;
    }
    float* dst = &qr_s[row][hd*20];
    #pragma unroll
    for (int j4 = 0; j4 < 4; ++j4)
      *(float4*)(dst + (j4<<2)) =
          make_float4(qr[4*j4], qr[4*j4+1], qr[4*j4+2], qr[4*j4+3]);
  }
  __syncthreads();

  // phase C: attn (reg kv x broadcast qr) + LePE, 2 rows/iter
  for (int rr = 0; rr < TILE_R; rr += 2) {
    const int r = rr + rh;
    const int i = i0 + r;
    const float* qrp = &qr_s[r][h*20];
    float acc = 0.f;
    #pragma unroll
    for (int j4 = 0; j4 < 4; ++j4) {
      float4 qa = *(const float4*)(qrp + (j4<<2));
      acc += qa.x*kvreg[4*j4+0] + qa.y*kvreg[4*j4+1]
           + qa.z*kvreg[4*j4+2] + qa.w*kvreg[4*j4+3];
    }
    acc *= z_s[r][h];
    const int hh  = i / NWW;
    const int www = i - hh*NWW;
    float lp = lb;
    #pragma unroll
    for (int dy = -1; dy <= 1; ++dy) {
      const int h2 = hh + dy;
      if (h2 < 0 || h2 >= NHH) continue;
      #pragma unroll
      for (int dx = -1; dx <= 1; ++dx) {
        const int w2 = www + dx;
        if (w2 < 0 || w2 >= NWW) continue;
        lp += wl[(dy+1)*3 + (dx+1)] * xb[((size_t)(h2*NWW + w2))*NC + ch];
      }
    }
    ot[r][ch] = acc + lp;
  }
  __syncthreads();
  // transposed write-out: contiguous float4 runs along i per channel
  const int ch2 = tid >> 1;
  const int ihalf = tid & 1;
  float* ob = outp + ((size_t)b*NC + ch2)*NNN + i0 + ihalf*32;
  #pragma unroll
  for (int rr4 = 0; rr4 < 32; rr4 += 4) {
    const int rbase = ihalf*32 + rr4;
    *(float4*)(ob + rr4) = make_float4(ot[rbase+0][ch2], ot[rbase+1][ch2],
                                       ot[rbase+2][ch2], ot[rbase+3][ch2]);
  }
}

// ---------------------------------------------------------------------------
extern "C" void kernel_launch(void* const* d_in, const int* in_sizes, int n_in,
                              void* d_out, int out_size, void* d_ws, size_t ws_size,
                              hipStream_t stream) {
  const float* x      = (const float*)d_in[0];
  const float* qk_w   = (const float*)d_in[1];
  const float* qk_b   = (const float*)d_in[2];
  const float* lepe_w = (const float*)d_in[3];
  const float* lepe_b = (const float*)d_in[4];
  float* outp = (float*)d_out;

  ushort* qbuf     = (ushort*)d_ws;                              // B*N*C bf16
  float* kv_part   = (float*)(qbuf + (size_t)NB*NNN*NC);         // B*NSLOTS*2048
  float* ksum_part = kv_part + (size_t)NB*NSLOTS*2048;           // B*NSLOTS*NC
  float* kvf       = ksum_part + (size_t)NB*NSLOTS*NC;           // B*2048
  float* kmean     = kvf + (size_t)NB*2048;                      // B*NC

  (void)hipMemsetAsync(kv_part, 0,
      ((size_t)NB*NSLOTS*2048 + (size_t)NB*NSLOTS*NC) * sizeof(float), stream);

  hipLaunchKernelGGL(k1_proj, dim3(NB*TPB), dim3(256), 0, stream,
                     x, qk_w, qk_b, qbuf, kv_part, ksum_part);
  hipLaunchKernelGGL(k_reduce, dim3(64), dim3(256), 0, stream,
                     kv_part, ksum_part, kvf, kmean);
  hipLaunchKernelGGL(k2_out, dim3(NB*TPB), dim3(256), 0, stream,
                     x, qbuf, kvf, kmean, lepe_w, lepe_b, outp);
}

// Round 3
// 318.814 us; speedup vs baseline: 2.5933x; 2.1844x over previous
//
#include <hip/hip_runtime.h>
#include <cstdint>
#include <cstddef>

#define NB 8
#define NC 128
#define NHH 160
#define NWW 160
#define NNN (NHH*NWW)        // 25600
#define TILE_R 64
#define TPB (NNN/TILE_R)     // 400 tiles per batch
#define NSLOTS 32
#define LN_B 0.14391156511f  // ln(10000)/64

typedef __attribute__((ext_vector_type(8))) short short8v;
typedef __attribute__((ext_vector_type(4))) short short4v;
typedef __attribute__((ext_vector_type(4))) float f32x4;
union B64x2 { short8v v8; short4v v4[2]; };

__device__ __forceinline__ float elup1(float y){ return y>0.f? y+1.f : __expf(y); }
__device__ __forceinline__ ushort f2bf(float f){ uint x=__float_as_uint(f); x+=0x7fffu+((x>>16)&1u); return (ushort)(x>>16); }
__device__ __forceinline__ float bfhi(uint u){ return __uint_as_float(u & 0xffff0000u); }
__device__ __forceinline__ float bflo(uint u){ return __uint_as_float(u << 16); }
__device__ __forceinline__ int divH(int i){ return (i*13108) >> 21; }   // i/160 for i<2^17

// ---------------------------------------------------------------------------
// ktable: rope cos/sin table [w][freq] (160 x 64 float2)
// ---------------------------------------------------------------------------
__global__ __launch_bounds__(256) void ktable(float2* __restrict__ rtab) {
  const int id = blockIdx.x*256 + threadIdx.x;
  if (id < NWW*64) {
    const int ww = id >> 6, f = id & 63;
    const float th = __expf(-LN_B * (float)f);
    float s, c; __sincosf((float)ww * th, &s, &c);
    rtab[id] = make_float2(c, s);
  }
}

// ---------------------------------------------------------------------------
// K1: MFMA projection GEMM (q,k); q->bf16 ws; k->rope->kv (MFMA) + ksum
// ---------------------------------------------------------------------------
__global__ __launch_bounds__(256) void k1_proj(
    const float* __restrict__ x, const float* __restrict__ qk_w,
    const float* __restrict__ qk_b, const float2* __restrict__ rtab,
    ushort* __restrict__ qout, float* __restrict__ kv_part,
    float* __restrict__ ksum_part)
{
  __shared__ __align__(16) ushort xbf[64][136];   // x tile bf16, row-major
  __shared__ __align__(16) ushort wch[64][136];   // W chunk bf16
  __shared__ __align__(16) ushort xtp[128][68];   // x tile bf16, transposed
  __shared__ __align__(16) ushort krt[128][68];   // roped k bf16, transposed
  __shared__ float ksum_lds[NC];

  const int blk  = blockIdx.x;
  const int b    = blk / TPB;
  const int tile = blk - b * TPB;
  const int i0   = tile * TILE_R;
  const int tid  = threadIdx.x;
  const int lane = tid & 63;
  const int wv   = tid >> 6;
  const int lg   = lane >> 4;
  const int ll   = lane & 15;
  const float* xb = x + (size_t)b*NNN*NC + (size_t)i0*NC;

  { // stage xbf (row-major) — coalesced float4 reads
    const float4* src = (const float4*)xb;
    for (int f = tid; f < TILE_R*NC/4; f += 256) {
      float4 v = src[f];
      ushort4 u = make_ushort4(f2bf(v.x), f2bf(v.y), f2bf(v.z), f2bf(v.w));
      *(ushort4*)&xbf[f >> 5][(f & 31) << 2] = u;
    }
  }
  if (tid < NC) ksum_lds[tid] = 0.f;
  __syncthreads();   // xbf ready

  // build xtp by in-LDS transpose (no global re-read)
  #pragma unroll
  for (int t = 0; t < 4; ++t) {
    const int task = tid + (t << 8);      // 0..1023
    const int c = task & 127, rg = task >> 7;
    ushort tmp[8];
    #pragma unroll
    for (int k2 = 0; k2 < 8; ++k2) tmp[k2] = xbf[(rg<<3)+k2][c];
    *(ushort4*)&xtp[c][(rg<<3)]   = make_ushort4(tmp[0],tmp[1],tmp[2],tmp[3]);
    *(ushort4*)&xtp[c][(rg<<3)+4] = make_ushort4(tmp[4],tmp[5],tmp[6],tmp[7]);
  }

  f32x4 kvacc[2];
  kvacc[0] = (f32x4){0.f,0.f,0.f,0.f};
  kvacc[1] = (f32x4){0.f,0.f,0.f,0.f};
  const int slot = blk & (NSLOTS-1);

  for (int chunk = 0; chunk < 4; ++chunk) {
    if (chunk) __syncthreads();   // prior readers of wch/krt done
    { // stage W chunk rows [chunk*64, +64) as bf16
      const float4* wsrc = (const float4*)(qk_w + (size_t)chunk*64*NC);
      for (int f = tid; f < 64*NC/4; f += 256) {
        float4 v = wsrc[f];
        ushort4 u = make_ushort4(f2bf(v.x), f2bf(v.y), f2bf(v.z), f2bf(v.w));
        *(ushort4*)&wch[f >> 5][(f & 31) << 2] = u;
      }
    }
    __syncthreads();

    // GEMM: wave wv owns rows 16wv..16wv+15; 4 n-tiles; K=128
    f32x4 acc[4];
    acc[0]=acc[1]=acc[2]=acc[3]=(f32x4){0.f,0.f,0.f,0.f};
    #pragma unroll
    for (int ks = 0; ks < 4; ++ks) {
      short8v a = *(const short8v*)&xbf[(wv<<4) + ll][(ks<<5) + (lg<<3)];
      #pragma unroll
      for (int nt = 0; nt < 4; ++nt) {
        short8v bb = *(const short8v*)&wch[(nt<<4) + ll][(ks<<5) + (lg<<3)];
        acc[nt] = __builtin_amdgcn_mfma_f32_16x16x32_bf16(a, bb, acc[nt], 0, 0, 0);
      }
    }

    const int row0 = (wv<<4) + (lg<<2);
    if (chunk < 2) {
      // q epilogue: bias + elu+1 -> bf16 store
      #pragma unroll
      for (int nt = 0; nt < 4; ++nt) {
        const int cg = (chunk<<6) + (nt<<4) + ll;
        const float bias = qk_b[cg];
        #pragma unroll
        for (int r = 0; r < 4; ++r) {
          float v = elup1(acc[nt][r] + bias);
          qout[((size_t)b*NNN + (size_t)(i0 + row0 + r))*NC + cg] = f2bf(v);
        }
      }
    } else {
      // k epilogue: bias + elu+1, ksum, rope (table), transposed bf16 store
      #pragma unroll
      for (int nt = 0; nt < 4; ++nt) {
        const int kc = ((chunk-2)<<6) + (nt<<4) + ll;
        const float bias = qk_b[NC + kc];
        float kk[4]; float ss = 0.f;
        #pragma unroll
        for (int r = 0; r < 4; ++r) { kk[r] = elup1(acc[nt][r] + bias); ss += kk[r]; }
        atomicAdd(&ksum_lds[kc], ss);
        ushort rb[4];
        #pragma unroll
        for (int r = 0; r < 4; ++r) {
          float p = __shfl_xor(kk[r], 1);
          const int i = i0 + row0 + r;
          const int wf = i - divH(i)*NWW;
          float2 cs = rtab[wf*64 + (kc >> 1)];
          float kr = (kc & 1) ? (p*cs.y + kk[r]*cs.x) : (kk[r]*cs.x - p*cs.y);
          rb[r] = f2bf(kr);
        }
        *(uint*)&krt[kc][row0]   = (uint)rb[0] | ((uint)rb[1] << 16);
        *(uint*)&krt[kc][row0+2] = (uint)rb[2] | ((uint)rb[3] << 16);
      }
      __syncthreads();   // krt tile ready
      const int h  = ((chunk-2)<<2) + wv;
      const int e2 = chunk - 2;
      #pragma unroll
      for (int ks = 0; ks < 2; ++ks) {
        const int rb2 = (ks<<5) + (lg<<3);
        B64x2 ua, ub;
        ua.v4[0] = *(const short4v*)&krt[(h<<4) + ll][rb2];
        ua.v4[1] = *(const short4v*)&krt[(h<<4) + ll][rb2+4];
        ub.v4[0] = *(const short4v*)&xtp[(h<<4) + ll][rb2];
        ub.v4[1] = *(const short4v*)&xtp[(h<<4) + ll][rb2+4];
        kvacc[e2] = __builtin_amdgcn_mfma_f32_16x16x32_bf16(ua.v8, ub.v8, kvacc[e2], 0, 0, 0);
      }
    }
  }

  { // kv partial atomics: lane holds kv_h[d=(lg*4+r)][e=ll]
    float* kvp = kv_part + ((size_t)b*NSLOTS + slot) * 2048;
    #pragma unroll
    for (int e2 = 0; e2 < 2; ++e2) {
      const int h = (e2<<2) + wv;
      #pragma unroll
      for (int r = 0; r < 4; ++r) {
        const int d = (lg<<2) + r;
        atomicAdd(&kvp[(h<<8) + (d<<4) + ll], kvacc[e2][r]);
      }
    }
  }
  __syncthreads();
  if (tid < NC) atomicAdd(&ksum_part[((size_t)b*NSLOTS + slot)*NC + tid], ksum_lds[tid]);
}

// ---------------------------------------------------------------------------
// Kred: reduce slots -> kv (scaled 1/n) and kmean
// ---------------------------------------------------------------------------
__global__ __launch_bounds__(256) void k_reduce(
    const float* __restrict__ kv_part, const float* __restrict__ ksum_part,
    float* __restrict__ kvf, float* __restrict__ kmean)
{
  const int gtid = blockIdx.x * 256 + threadIdx.x;
  const int b = gtid >> 11;
  const int cidx = gtid & 2047;
  float s = 0.f;
  for (int sl = 0; sl < NSLOTS; ++sl)
    s += kv_part[((size_t)b*NSLOTS + sl)*2048 + cidx];
  kvf[(size_t)b*2048 + cidx] = s * (1.f/25600.f);
  if (cidx < NC) {
    float t = 0.f;
    for (int sl = 0; sl < NSLOTS; ++sl)
      t += ksum_part[((size_t)b*NSLOTS + sl)*NC + cidx];
    kmean[(size_t)b*NC + cidx] = t * (1.f/25600.f);
  }
}

// ---------------------------------------------------------------------------
// K2: rope(q)+z phase (table), branch-free fused attn+LePE, direct stores
// ---------------------------------------------------------------------------
__global__ __launch_bounds__(256) void k2_out(
    const float* __restrict__ x, const ushort* __restrict__ qbuf,
    const float* __restrict__ kvf, const float* __restrict__ kmean,
    const float* __restrict__ lepe_w, const float* __restrict__ lepe_b,
    const float2* __restrict__ rtab, float* __restrict__ outp)
{
  __shared__ __align__(16) ushort qr_s[64][128];  // roped q, bf16, head stride 16
  __shared__ float z_s[64][8];
  __shared__ float km_s[NC];

  const int blk  = blockIdx.x;
  const int b    = blk / TPB;
  const int tile = blk - b * TPB;
  const int i0   = tile * TILE_R;
  const int tid  = threadIdx.x;

  if (tid < NC) km_s[tid] = kmean[(size_t)b*NC + tid];

  // phase-C identity: thread = (channel ch, row-half rh)
  const int ch = tid >> 1, rh = tid & 1;
  const int hC = ch >> 4, cl = ch & 15;
  float kvreg[16];
  #pragma unroll
  for (int d = 0; d < 16; ++d)
    kvreg[d] = kvf[(size_t)b*2048 + (hC<<8) + (d<<4) + cl];
  float wl[9];
  #pragma unroll
  for (int t = 0; t < 9; ++t) wl[t] = lepe_w[ch*9 + t];
  const float lb = lepe_b[ch];
  const float* xb = x + (size_t)b*NNN*NC;
  __syncthreads();   // km_s ready

  // phase B: rope + z; task = (row, head)
  #pragma unroll
  for (int t2 = 0; t2 < 2; ++t2) {
    const int id  = tid + (t2 << 8);
    const int row = id >> 3;
    const int hd  = id & 7;
    const ushort* qp = qbuf + ((size_t)b*NNN + (size_t)(i0 + row))*NC + (hd<<4);
    uint4 u0 = *(const uint4*)qp;
    uint4 u1 = *(const uint4*)(qp + 8);
    float q[16];
    q[0]=bflo(u0.x); q[1]=bfhi(u0.x); q[2]=bflo(u0.y); q[3]=bfhi(u0.y);
    q[4]=bflo(u0.z); q[5]=bfhi(u0.z); q[6]=bflo(u0.w); q[7]=bfhi(u0.w);
    q[8]=bflo(u1.x); q[9]=bfhi(u1.x); q[10]=bflo(u1.y); q[11]=bfhi(u1.y);
    q[12]=bflo(u1.z); q[13]=bfhi(u1.z); q[14]=bflo(u1.w); q[15]=bfhi(u1.w);
    float zp = 0.f;
    #pragma unroll
    for (int j = 0; j < 16; ++j) zp += q[j] * km_s[(hd<<4) + j];
    z_s[row][hd] = 1.f / (zp + 1e-6f);
    const int i = i0 + row;
    const int ww = i - divH(i)*NWW;
    const float2* tp = rtab + ww*64 + (hd<<3);
    uint qpk[8];
    #pragma unroll
    for (int j = 0; j < 8; ++j) {
      float2 cs = tp[j];
      float e = q[2*j]*cs.x - q[2*j+1]*cs.y;
      float o = q[2*j]*cs.y + q[2*j+1]*cs.x;
      qpk[j] = (uint)f2bf(e) | ((uint)f2bf(o) << 16);
    }
    *(uint4*)&qr_s[row][hd<<4]     = make_uint4(qpk[0],qpk[1],qpk[2],qpk[3]);
    *(uint4*)&qr_s[row][(hd<<4)+8] = make_uint4(qpk[4],qpk[5],qpk[6],qpk[7]);
  }
  __syncthreads();

  // phase C: 32 rows per thread, branch-free LePE, direct float4 stores
  const int ibase = i0 + (rh << 5);
  int hh = divH(ibase);
  int ww = ibase - hh*NWW;
  float* ob = outp + ((size_t)b*NC + ch)*NNN + ibase;
  for (int j4 = 0; j4 < 8; ++j4) {
    float4 ov;
    #pragma unroll
    for (int jj = 0; jj < 4; ++jj) {
      const int r = (rh<<5) + (j4<<2) + jj;
      const uint4 qa = *(const uint4*)&qr_s[r][hC<<4];
      const uint4 qb = *(const uint4*)&qr_s[r][(hC<<4)+8];
      float acc;
      acc  = bflo(qa.x)*kvreg[0]  + bfhi(qa.x)*kvreg[1];
      acc += bflo(qa.y)*kvreg[2]  + bfhi(qa.y)*kvreg[3];
      acc += bflo(qa.z)*kvreg[4]  + bfhi(qa.z)*kvreg[5];
      acc += bflo(qa.w)*kvreg[6]  + bfhi(qa.w)*kvreg[7];
      acc += bflo(qb.x)*kvreg[8]  + bfhi(qb.x)*kvreg[9];
      acc += bflo(qb.y)*kvreg[10] + bfhi(qb.y)*kvreg[11];
      acc += bflo(qb.z)*kvreg[12] + bfhi(qb.z)*kvreg[13];
      acc += bflo(qb.w)*kvreg[14] + bfhi(qb.w)*kvreg[15];
      acc *= z_s[r][hC];
      // LePE: branch-free (clamped addr, zeroed weight)
      const int hm = hh > 0   ? hh-1 : 0;
      const int hp = hh < 159 ? hh+1 : 159;
      const int wm = ww > 0   ? ww-1 : 0;
      const int wp = ww < 159 ? ww+1 : 159;
      const float fy0 = hh > 0   ? 1.f : 0.f;
      const float fy2 = hh < 159 ? 1.f : 0.f;
      const float fx0 = ww > 0   ? 1.f : 0.f;
      const float fx2 = ww < 159 ? 1.f : 0.f;
      const float* r0 = xb + (size_t)(hm*NWW)*NC + ch;
      const float* r1 = xb + (size_t)(hh*NWW)*NC + ch;
      const float* r2 = xb + (size_t)(hp*NWW)*NC + ch;
      float lp = lb;
      lp += (fy0*fx0*wl[0]) * r0[(size_t)wm*NC];
      lp += (fy0*    wl[1]) * r0[(size_t)ww*NC];
      lp += (fy0*fx2*wl[2]) * r0[(size_t)wp*NC];
      lp += (fx0*    wl[3]) * r1[(size_t)wm*NC];
      lp += (        wl[4]) * r1[(size_t)ww*NC];
      lp += (fx2*    wl[5]) * r1[(size_t)wp*NC];
      lp += (fy2*fx0*wl[6]) * r2[(size_t)wm*NC];
      lp += (fy2*    wl[7]) * r2[(size_t)ww*NC];
      lp += (fy2*fx2*wl[8]) * r2[(size_t)wp*NC];
      (&ov.x)[jj] = acc + lp;
      const int cy = (ww == NWW-1) ? 1 : 0;
      hh += cy;
      ww = cy ? 0 : ww + 1;
    }
    *(float4*)(ob + (j4<<2)) = ov;
  }
}

// ---------------------------------------------------------------------------
extern "C" void kernel_launch(void* const* d_in, const int* in_sizes, int n_in,
                              void* d_out, int out_size, void* d_ws, size_t ws_size,
                              hipStream_t stream) {
  const float* x      = (const float*)d_in[0];
  const float* qk_w   = (const float*)d_in[1];
  const float* qk_b   = (const float*)d_in[2];
  const float* lepe_w = (const float*)d_in[3];
  const float* lepe_b = (const float*)d_in[4];
  float* outp = (float*)d_out;

  ushort* qbuf     = (ushort*)d_ws;                              // B*N*C bf16
  float* kv_part   = (float*)(qbuf + (size_t)NB*NNN*NC);         // B*NSLOTS*2048
  float* ksum_part = kv_part + (size_t)NB*NSLOTS*2048;           // B*NSLOTS*NC
  float* kvf       = ksum_part + (size_t)NB*NSLOTS*NC;           // B*2048
  float* kmean     = kvf + (size_t)NB*2048;                      // B*NC
  float2* rtab     = (float2*)(kmean + (size_t)NB*NC);           // 160*64

  (void)hipMemsetAsync(kv_part, 0,
      ((size_t)NB*NSLOTS*2048 + (size_t)NB*NSLOTS*NC) * sizeof(float), stream);

  hipLaunchKernelGGL(ktable, dim3(40), dim3(256), 0, stream, rtab);
  hipLaunchKernelGGL(k1_proj, dim3(NB*TPB), dim3(256), 0, stream,
                     x, qk_w, qk_b, rtab, qbuf, kv_part, ksum_part);
  hipLaunchKernelGGL(k_reduce, dim3(64), dim3(256), 0, stream,
                     kv_part, ksum_part, kvf, kmean);
  hipLaunchKernelGGL(k2_out, dim3(NB*TPB), dim3(256), 0, stream,
                     x, qbuf, kvf, kmean, lepe_w, lepe_b, rtab, outp);
}

// Round 4
// 315.397 us; speedup vs baseline: 2.6214x; 1.0108x over previous
//
#include <hip/hip_runtime.h>
#include <cstdint>
#include <cstddef>

#define NB 8
#define NC 128
#define NHH 160
#define NWW 160
#define NNN (NHH*NWW)        // 25600
#define TILE_R 64
#define TPB (NNN/TILE_R)     // 400 tiles per batch
#define NSLOTS 32
#define LN_B 0.14391156511f  // ln(10000)/64

typedef __attribute__((ext_vector_type(8))) short short8v;
typedef __attribute__((ext_vector_type(4))) short short4v;
typedef __attribute__((ext_vector_type(4))) float f32x4;
union B64x2 { short8v v8; short4v v4[2]; ushort u[8]; };

__device__ __forceinline__ float elup1(float y){ return y>0.f? y+1.f : __expf(y); }
__device__ __forceinline__ ushort f2bf(float f){ uint x=__float_as_uint(f); x+=0x7fffu+((x>>16)&1u); return (ushort)(x>>16); }
__device__ __forceinline__ float bfhi(uint u){ return __uint_as_float(u & 0xffff0000u); }
__device__ __forceinline__ float bflo(uint u){ return __uint_as_float(u << 16); }
__device__ __forceinline__ int divH(int i){ return (i*13108) >> 21; }   // i/160 for i<2^17

// ---------------------------------------------------------------------------
// ktable: rope cos/sin table [w][freq] (160 x 64 float2)
// ---------------------------------------------------------------------------
__global__ __launch_bounds__(256) void ktable(float2* __restrict__ rtab) {
  const int id = blockIdx.x*256 + threadIdx.x;
  if (id < NWW*64) {
    const int ww = id >> 6, f = id & 63;
    const float th = __expf(-LN_B * (float)f);
    float s, c; __sincosf((float)ww * th, &s, &c);
    rtab[id] = make_float2(c, s);
  }
}

// ---------------------------------------------------------------------------
// K1: k-projection MFMA GEMM; k->rope->kv (MFMA) + ksum partials
// ---------------------------------------------------------------------------
__global__ __launch_bounds__(256) void k1_proj(
    const float* __restrict__ x, const float* __restrict__ qk_w,
    const float* __restrict__ qk_b, const float2* __restrict__ rtab,
    float* __restrict__ kv_part, float* __restrict__ ksum_part)
{
  __shared__ __align__(16) ushort xbf[64][136];   // x tile bf16 (GEMM A + v cols)
  __shared__ __align__(16) ushort wch[64][136];   // Wk chunk bf16
  __shared__ __align__(16) ushort krt[128][68];   // roped k bf16, transposed
  __shared__ float ksum_lds[NC];

  const int blk  = blockIdx.x;
  const int b    = blk / TPB;
  const int tile = blk - b * TPB;
  const int i0   = tile * TILE_R;
  const int tid  = threadIdx.x;
  const int lane = tid & 63;
  const int wv   = tid >> 6;
  const int lg   = lane >> 4;
  const int ll   = lane & 15;
  const float* xb = x + (size_t)b*NNN*NC + (size_t)i0*NC;

  { // stage xbf (row-major) — coalesced float4 reads
    const float4* src = (const float4*)xb;
    for (int f = tid; f < TILE_R*NC/4; f += 256) {
      float4 v = src[f];
      ushort4 u = make_ushort4(f2bf(v.x), f2bf(v.y), f2bf(v.z), f2bf(v.w));
      *(ushort4*)&xbf[f >> 5][(f & 31) << 2] = u;
    }
  }
  if (tid < NC) ksum_lds[tid] = 0.f;

  f32x4 kvacc[2];
  kvacc[0] = (f32x4){0.f,0.f,0.f,0.f};
  kvacc[1] = (f32x4){0.f,0.f,0.f,0.f};
  const int slot = blk & (NSLOTS-1);

  for (int chunk = 0; chunk < 2; ++chunk) {
    if (chunk) __syncthreads();   // GEMM reads of wch (prev chunk) done
    { // stage Wk chunk: qk_w rows [128 + chunk*64, +64) as bf16
      const float4* wsrc = (const float4*)(qk_w + (size_t)(chunk+2)*64*NC);
      for (int f = tid; f < 64*NC/4; f += 256) {
        float4 v = wsrc[f];
        ushort4 u = make_ushort4(f2bf(v.x), f2bf(v.y), f2bf(v.z), f2bf(v.w));
        *(ushort4*)&wch[f >> 5][(f & 31) << 2] = u;
      }
    }
    __syncthreads();   // (iter0: also covers xbf/ksum init)

    // GEMM: wave wv owns rows 16wv..16wv+15; 4 n-tiles; K=128
    f32x4 acc[4];
    acc[0]=acc[1]=acc[2]=acc[3]=(f32x4){0.f,0.f,0.f,0.f};
    #pragma unroll
    for (int ks = 0; ks < 4; ++ks) {
      short8v a = *(const short8v*)&xbf[(wv<<4) + ll][(ks<<5) + (lg<<3)];
      #pragma unroll
      for (int nt = 0; nt < 4; ++nt) {
        short8v bb = *(const short8v*)&wch[(nt<<4) + ll][(ks<<5) + (lg<<3)];
        acc[nt] = __builtin_amdgcn_mfma_f32_16x16x32_bf16(a, bb, acc[nt], 0, 0, 0);
      }
    }

    const int row0 = (wv<<4) + (lg<<2);
    // k epilogue: bias + elu+1, ksum, rope (table), transposed bf16 store
    #pragma unroll
    for (int nt = 0; nt < 4; ++nt) {
      const int kc = (chunk<<6) + (nt<<4) + ll;
      const float bias = qk_b[NC + kc];
      float kk[4]; float ss = 0.f;
      #pragma unroll
      for (int r = 0; r < 4; ++r) { kk[r] = elup1(acc[nt][r] + bias); ss += kk[r]; }
      atomicAdd(&ksum_lds[kc], ss);
      ushort rb[4];
      #pragma unroll
      for (int r = 0; r < 4; ++r) {
        float p = __shfl_xor(kk[r], 1);
        const int i = i0 + row0 + r;
        const int wf = i - divH(i)*NWW;
        float2 cs = rtab[wf*64 + (kc >> 1)];
        float kr = (kc & 1) ? (p*cs.y + kk[r]*cs.x) : (kk[r]*cs.x - p*cs.y);
        rb[r] = f2bf(kr);
      }
      *(uint*)&krt[kc][row0]   = (uint)rb[0] | ((uint)rb[1] << 16);
      *(uint*)&krt[kc][row0+2] = (uint)rb[2] | ((uint)rb[3] << 16);
    }
    __syncthreads();   // krt tile ready

    // kv via MFMA: head h = chunk*4+wv; kv_h += krt_h^T-slices . v_h
    const int h = (chunk<<2) + wv;
    #pragma unroll
    for (int ks = 0; ks < 2; ++ks) {
      const int rb2 = (ks<<5) + (lg<<3);
      B64x2 ua, ub;
      ua.v4[0] = *(const short4v*)&krt[(h<<4) + ll][rb2];
      ua.v4[1] = *(const short4v*)&krt[(h<<4) + ll][rb2+4];
      #pragma unroll
      for (int u = 0; u < 8; ++u)       // v columns from xbf (u16 col reads)
        ub.u[u] = xbf[rb2 + u][(h<<4) + ll];
      kvacc[chunk] = __builtin_amdgcn_mfma_f32_16x16x32_bf16(ua.v8, ub.v8, kvacc[chunk], 0, 0, 0);
    }
  }

  { // kv partial atomics: lane holds kv_h[d=(lg*4+r)][e=ll]
    float* kvp = kv_part + ((size_t)b*NSLOTS + slot) * 2048;
    #pragma unroll
    for (int e2 = 0; e2 < 2; ++e2) {
      const int h = (e2<<2) + wv;
      #pragma unroll
      for (int r = 0; r < 4; ++r) {
        const int d = (lg<<2) + r;
        atomicAdd(&kvp[(h<<8) + (d<<4) + ll], kvacc[e2][r]);
      }
    }
  }
  __syncthreads();
  if (tid < NC) atomicAdd(&ksum_part[((size_t)b*NSLOTS + slot)*NC + tid], ksum_lds[tid]);
}

// ---------------------------------------------------------------------------
// Kred: reduce slots -> kv (scaled 1/n) and kmean
// ---------------------------------------------------------------------------
__global__ __launch_bounds__(256) void k_reduce(
    const float* __restrict__ kv_part, const float* __restrict__ ksum_part,
    float* __restrict__ kvf, float* __restrict__ kmean)
{
  const int gtid = blockIdx.x * 256 + threadIdx.x;
  const int b = gtid >> 11;
  const int cidx = gtid & 2047;
  float s = 0.f;
  for (int sl = 0; sl < NSLOTS; ++sl)
    s += kv_part[((size_t)b*NSLOTS + sl)*2048 + cidx];
  kvf[(size_t)b*2048 + cidx] = s * (1.f/25600.f);
  if (cidx < NC) {
    float t = 0.f;
    for (int sl = 0; sl < NSLOTS; ++sl)
      t += ksum_part[((size_t)b*NSLOTS + sl)*NC + cidx];
    kmean[(size_t)b*NC + cidx] = t * (1.f/25600.f);
  }
}

// ---------------------------------------------------------------------------
// K2: q-GEMM (MFMA, recompute) + rope/z + attn + LePE + transposed store
// ---------------------------------------------------------------------------
__global__ __launch_bounds__(256) void k2_out(
    const float* __restrict__ x, const float* __restrict__ qk_w,
    const float* __restrict__ qk_b, const float* __restrict__ kvf,
    const float* __restrict__ kmean, const float* __restrict__ lepe_w,
    const float* __restrict__ lepe_b, const float2* __restrict__ rtab,
    float* __restrict__ outp)
{
  __shared__ __align__(16) ushort xs[64][136];   // GEMM A; z_s aliases after GEMM
  __shared__ __align__(16) ushort wq[64][136];   // Wq chunk
  __shared__ __align__(16) ushort q_s[64][136];  // q (then roped q) bf16
  __shared__ float km_s[NC];
  float (*z_s)[8] = (float(*)[8])&xs[0][0];      // alias (xs dead after GEMM)

  const int blk  = blockIdx.x;
  const int b    = blk / TPB;
  const int tile = blk - b * TPB;
  const int i0   = tile * TILE_R;
  const int tid  = threadIdx.x;
  const int lane = tid & 63;
  const int wv   = tid >> 6;
  const int lg   = lane >> 4;
  const int ll   = lane & 15;
  const float* xb  = x + (size_t)b*NNN*NC;
  const float* xbt = xb + (size_t)i0*NC;

  if (tid < NC) km_s[tid] = kmean[(size_t)b*NC + tid];

  { // stage xs bf16 tile
    const float4* src = (const float4*)xbt;
    for (int f = tid; f < TILE_R*NC/4; f += 256) {
      float4 v = src[f];
      ushort4 u = make_ushort4(f2bf(v.x), f2bf(v.y), f2bf(v.z), f2bf(v.w));
      *(ushort4*)&xs[f >> 5][(f & 31) << 2] = u;
    }
  }

  // phase-C identity + early global loads (in flight through GEMM)
  const int ch = tid >> 1, rh = tid & 1;
  const int hC = ch >> 4, cl = ch & 15;
  float kvreg[16];
  #pragma unroll
  for (int d = 0; d < 16; ++d)
    kvreg[d] = kvf[(size_t)b*2048 + (hC<<8) + (d<<4) + cl];
  float wl[9];
  #pragma unroll
  for (int t = 0; t < 9; ++t) wl[t] = lepe_w[ch*9 + t];
  const float lb = lepe_b[ch];

  // q-GEMM: 2 chunks of 64 output cols
  for (int chunk = 0; chunk < 2; ++chunk) {
    if (chunk) __syncthreads();
    {
      const float4* wsrc = (const float4*)(qk_w + (size_t)chunk*64*NC);
      for (int f = tid; f < 64*NC/4; f += 256) {
        float4 v = wsrc[f];
        ushort4 u = make_ushort4(f2bf(v.x), f2bf(v.y), f2bf(v.z), f2bf(v.w));
        *(ushort4*)&wq[f >> 5][(f & 31) << 2] = u;
      }
    }
    __syncthreads();

    f32x4 acc[4];
    acc[0]=acc[1]=acc[2]=acc[3]=(f32x4){0.f,0.f,0.f,0.f};
    #pragma unroll
    for (int ks = 0; ks < 4; ++ks) {
      short8v a = *(const short8v*)&xs[(wv<<4) + ll][(ks<<5) + (lg<<3)];
      #pragma unroll
      for (int nt = 0; nt < 4; ++nt) {
        short8v bb = *(const short8v*)&wq[(nt<<4) + ll][(ks<<5) + (lg<<3)];
        acc[nt] = __builtin_amdgcn_mfma_f32_16x16x32_bf16(a, bb, acc[nt], 0, 0, 0);
      }
    }
    const int row0 = (wv<<4) + (lg<<2);
    #pragma unroll
    for (int nt = 0; nt < 4; ++nt) {
      const int cg = (chunk<<6) + (nt<<4) + ll;
      const float bias = qk_b[cg];
      #pragma unroll
      for (int r = 0; r < 4; ++r)
        q_s[row0 + r][cg] = f2bf(elup1(acc[nt][r] + bias));
    }
  }
  __syncthreads();   // q_s complete; xs dead -> z_s alias live

  // phase B: rope + z; task = (row, head); in-place q_s rewrite
  #pragma unroll
  for (int t2 = 0; t2 < 2; ++t2) {
    const int id  = tid + (t2 << 8);
    const int row = id >> 3;
    const int hd  = id & 7;
    uint4 u0 = *(const uint4*)&q_s[row][hd<<4];
    uint4 u1 = *(const uint4*)&q_s[row][(hd<<4)+8];
    float q[16];
    q[0]=bflo(u0.x); q[1]=bfhi(u0.x); q[2]=bflo(u0.y); q[3]=bfhi(u0.y);
    q[4]=bflo(u0.z); q[5]=bfhi(u0.z); q[6]=bflo(u0.w); q[7]=bfhi(u0.w);
    q[8]=bflo(u1.x); q[9]=bfhi(u1.x); q[10]=bflo(u1.y); q[11]=bfhi(u1.y);
    q[12]=bflo(u1.z); q[13]=bfhi(u1.z); q[14]=bflo(u1.w); q[15]=bfhi(u1.w);
    float zp = 0.f;
    #pragma unroll
    for (int j = 0; j < 16; ++j) zp += q[j] * km_s[(hd<<4) + j];
    z_s[row][hd] = 1.f / (zp + 1e-6f);
    const int i = i0 + row;
    const int ww = i - divH(i)*NWW;
    const float2* tp = rtab + ww*64 + (hd<<3);
    uint qpk[8];
    #pragma unroll
    for (int j = 0; j < 8; ++j) {
      float2 cs = tp[j];
      float e = q[2*j]*cs.x - q[2*j+1]*cs.y;
      float o = q[2*j]*cs.y + q[2*j+1]*cs.x;
      qpk[j] = (uint)f2bf(e) | ((uint)f2bf(o) << 16);
    }
    *(uint4*)&q_s[row][hd<<4]     = make_uint4(qpk[0],qpk[1],qpk[2],qpk[3]);
    *(uint4*)&q_s[row][(hd<<4)+8] = make_uint4(qpk[4],qpk[5],qpk[6],qpk[7]);
  }
  __syncthreads();

  // phase C: 32 rows per thread, branch-free LePE, direct float4 stores
  const int ibase = i0 + (rh << 5);
  int hh = divH(ibase);
  int ww = ibase - hh*NWW;
  float* ob = outp + ((size_t)b*NC + ch)*NNN + ibase;
  for (int j4 = 0; j4 < 8; ++j4) {
    float4 ov;
    #pragma unroll
    for (int jj = 0; jj < 4; ++jj) {
      const int r = (rh<<5) + (j4<<2) + jj;
      const uint4 qa = *(const uint4*)&q_s[r][hC<<4];
      const uint4 qb = *(const uint4*)&q_s[r][(hC<<4)+8];
      float acc;
      acc  = bflo(qa.x)*kvreg[0]  + bfhi(qa.x)*kvreg[1];
      acc += bflo(qa.y)*kvreg[2]  + bfhi(qa.y)*kvreg[3];
      acc += bflo(qa.z)*kvreg[4]  + bfhi(qa.z)*kvreg[5];
      acc += bflo(qa.w)*kvreg[6]  + bfhi(qa.w)*kvreg[7];
      acc += bflo(qb.x)*kvreg[8]  + bfhi(qb.x)*kvreg[9];
      acc += bflo(qb.y)*kvreg[10] + bfhi(qb.y)*kvreg[11];
      acc += bflo(qb.z)*kvreg[12] + bfhi(qb.z)*kvreg[13];
      acc += bflo(qb.w)*kvreg[14] + bfhi(qb.w)*kvreg[15];
      acc *= z_s[r][hC];
      const int hm = hh > 0   ? hh-1 : 0;
      const int hp = hh < 159 ? hh+1 : 159;
      const int wm = ww > 0   ? ww-1 : 0;
      const int wp = ww < 159 ? ww+1 : 159;
      const float fy0 = hh > 0   ? 1.f : 0.f;
      const float fy2 = hh < 159 ? 1.f : 0.f;
      const float fx0 = ww > 0   ? 1.f : 0.f;
      const float fx2 = ww < 159 ? 1.f : 0.f;
      const float* r0 = xb + (size_t)(hm*NWW)*NC + ch;
      const float* r1 = xb + (size_t)(hh*NWW)*NC + ch;
      const float* r2 = xb + (size_t)(hp*NWW)*NC + ch;
      float lp = lb;
      lp += (fy0*fx0*wl[0]) * r0[(size_t)wm*NC];
      lp += (fy0*    wl[1]) * r0[(size_t)ww*NC];
      lp += (fy0*fx2*wl[2]) * r0[(size_t)wp*NC];
      lp += (fx0*    wl[3]) * r1[(size_t)wm*NC];
      lp += (        wl[4]) * r1[(size_t)ww*NC];
      lp += (fx2*    wl[5]) * r1[(size_t)wp*NC];
      lp += (fy2*fx0*wl[6]) * r2[(size_t)wm*NC];
      lp += (fy2*    wl[7]) * r2[(size_t)ww*NC];
      lp += (fy2*fx2*wl[8]) * r2[(size_t)wp*NC];
      (&ov.x)[jj] = acc + lp;
      const int cy = (ww == NWW-1) ? 1 : 0;
      hh += cy;
      ww = cy ? 0 : ww + 1;
    }
    *(float4*)(ob + (j4<<2)) = ov;
  }
}

// ---------------------------------------------------------------------------
extern "C" void kernel_launch(void* const* d_in, const int* in_sizes, int n_in,
                              void* d_out, int out_size, void* d_ws, size_t ws_size,
                              hipStream_t stream) {
  const float* x      = (const float*)d_in[0];
  const float* qk_w   = (const float*)d_in[1];
  const float* qk_b   = (const float*)d_in[2];
  const float* lepe_w = (const float*)d_in[3];
  const float* lepe_b = (const float*)d_in[4];
  float* outp = (float*)d_out;

  float* kv_part   = (float*)d_ws;                               // B*NSLOTS*2048
  float* ksum_part = kv_part + (size_t)NB*NSLOTS*2048;           // B*NSLOTS*NC
  float* kvf       = ksum_part + (size_t)NB*NSLOTS*NC;           // B*2048
  float* kmean     = kvf + (size_t)NB*2048;                      // B*NC
  float2* rtab     = (float2*)(kmean + (size_t)NB*NC);           // 160*64

  (void)hipMemsetAsync(kv_part, 0,
      ((size_t)NB*NSLOTS*2048 + (size_t)NB*NSLOTS*NC) * sizeof(float), stream);

  hipLaunchKernelGGL(ktable, dim3(40), dim3(256), 0, stream, rtab);
  hipLaunchKernelGGL(k1_proj, dim3(NB*TPB), dim3(256), 0, stream,
                     x, qk_w, qk_b, rtab, kv_part, ksum_part);
  hipLaunchKernelGGL(k_reduce, dim3(64), dim3(256), 0, stream,
                     kv_part, ksum_part, kvf, kmean);
  hipLaunchKernelGGL(k2_out, dim3(NB*TPB), dim3(256), 0, stream,
                     x, qk_w, qk_b, kvf, kmean, lepe_w, lepe_b, rtab, outp);
}

// Round 5
// 302.385 us; speedup vs baseline: 2.7342x; 1.0430x over previous
//
#include <hip/hip_runtime.h>
#include <cstdint>
#include <cstddef>

#define NB 8
#define NC 128
#define NHH 160
#define NWW 160
#define NNN (NHH*NWW)        // 25600
#define TILE_R 64
#define TPB (NNN/TILE_R)     // 400 tiles per batch
#define NSLOTS 32
#define LN_B 0.14391156511f  // ln(10000)/64

typedef __attribute__((ext_vector_type(8))) short short8v;
typedef __attribute__((ext_vector_type(4))) short short4v;
typedef __attribute__((ext_vector_type(4))) float f32x4;
union B64x2 { short8v v8; short4v v4[2]; ushort u[8]; };

__device__ __forceinline__ float elup1(float y){ return y>0.f? y+1.f : __expf(y); }
__device__ __forceinline__ ushort f2bf(float f){ uint x=__float_as_uint(f); x+=0x7fffu+((x>>16)&1u); return (ushort)(x>>16); }
__device__ __forceinline__ float bfhi(uint u){ return __uint_as_float(u & 0xffff0000u); }
__device__ __forceinline__ float bflo(uint u){ return __uint_as_float(u << 16); }
__device__ __forceinline__ int divH(int i){ return (i*13108) >> 21; }   // i/160 for i<2^17
__device__ __forceinline__ int iclamp(int v, int lo, int hi){ return v<lo?lo:(v>hi?hi:v); }

// ---------------------------------------------------------------------------
// wprep: qk_w fp32 -> bf16 (rows 0..127 = Wq, 128..255 = Wk)
// ---------------------------------------------------------------------------
__global__ __launch_bounds__(256) void wprep(const float* __restrict__ qk_w,
                                             ushort* __restrict__ wbf) {
  const int id = blockIdx.x*256 + threadIdx.x;
  if (id < 2*NC*NC) wbf[id] = f2bf(qk_w[id]);
}

// ---------------------------------------------------------------------------
// ktable: rope cos/sin table [w][freq] (160 x 64 float2)
// ---------------------------------------------------------------------------
__global__ __launch_bounds__(256) void ktable(float2* __restrict__ rtab) {
  const int id = blockIdx.x*256 + threadIdx.x;
  if (id < NWW*64) {
    const int ww = id >> 6, f = id & 63;
    const float th = __expf(-LN_B * (float)f);
    float s, c; __sincosf((float)ww * th, &s, &c);
    rtab[id] = make_float2(c, s);
  }
}

// ---------------------------------------------------------------------------
// K1: k-projection MFMA GEMM (W frags from global bf16); rope->kv + ksum
// ---------------------------------------------------------------------------
__global__ __launch_bounds__(256) void k1_proj(
    const float* __restrict__ x, const ushort* __restrict__ wbf,
    const float* __restrict__ qk_b, const float2* __restrict__ rtab,
    float* __restrict__ kv_part, float* __restrict__ ksum_part)
{
  __shared__ __align__(16) ushort xbf[64][136];   // x tile bf16 (GEMM A + v cols)
  __shared__ __align__(16) ushort krt[128][68];   // roped k bf16, transposed
  __shared__ float ksum_lds[NC];

  const int blk  = blockIdx.x;
  const int b    = blk / TPB;
  const int tile = blk - b * TPB;
  const int i0   = tile * TILE_R;
  const int tid  = threadIdx.x;
  const int lane = tid & 63;
  const int wv   = tid >> 6;
  const int lg   = lane >> 4;
  const int ll   = lane & 15;
  const float* xb = x + (size_t)b*NNN*NC + (size_t)i0*NC;

  { // stage xbf (row-major) — coalesced float4 reads
    const float4* src = (const float4*)xb;
    for (int f = tid; f < TILE_R*NC/4; f += 256) {
      float4 v = src[f];
      ushort4 u = make_ushort4(f2bf(v.x), f2bf(v.y), f2bf(v.z), f2bf(v.w));
      *(ushort4*)&xbf[f >> 5][(f & 31) << 2] = u;
    }
  }
  if (tid < NC) ksum_lds[tid] = 0.f;
  __syncthreads();

  // GEMM: all 128 k cols in one pass; B-frags from global bf16 (L1/L2-hot)
  f32x4 acc[8];
  #pragma unroll
  for (int t = 0; t < 8; ++t) acc[t] = (f32x4){0.f,0.f,0.f,0.f};
  #pragma unroll
  for (int ks = 0; ks < 4; ++ks) {
    short8v a = *(const short8v*)&xbf[(wv<<4) + ll][(ks<<5) + (lg<<3)];
    #pragma unroll
    for (int nt = 0; nt < 8; ++nt) {
      short8v bb = *(const short8v*)(wbf + (size_t)(NC + (nt<<4) + ll)*NC + (ks<<5) + (lg<<3));
      acc[nt] = __builtin_amdgcn_mfma_f32_16x16x32_bf16(a, bb, acc[nt], 0, 0, 0);
    }
  }

  const int row0 = (wv<<4) + (lg<<2);
  // k epilogue: bias + elu+1, ksum, rope (table), transposed bf16 store
  #pragma unroll
  for (int nt = 0; nt < 8; ++nt) {
    const int kc = (nt<<4) + ll;
    const float bias = qk_b[NC + kc];
    float kk[4]; float ss = 0.f;
    #pragma unroll
    for (int r = 0; r < 4; ++r) { kk[r] = elup1(acc[nt][r] + bias); ss += kk[r]; }
    atomicAdd(&ksum_lds[kc], ss);
    ushort rb[4];
    #pragma unroll
    for (int r = 0; r < 4; ++r) {
      float p = __shfl_xor(kk[r], 1);
      const int i = i0 + row0 + r;
      const int wf = i - divH(i)*NWW;
      float2 cs = rtab[wf*64 + (kc >> 1)];
      float kr = (kc & 1) ? (p*cs.y + kk[r]*cs.x) : (kk[r]*cs.x - p*cs.y);
      rb[r] = f2bf(kr);
    }
    *(uint*)&krt[kc][row0]   = (uint)rb[0] | ((uint)rb[1] << 16);
    *(uint*)&krt[kc][row0+2] = (uint)rb[2] | ((uint)rb[3] << 16);
  }
  __syncthreads();   // krt ready; ksum atomics done

  // kv via MFMA: heads h = wv and wv+4
  f32x4 kvacc[2];
  kvacc[0] = (f32x4){0.f,0.f,0.f,0.f};
  kvacc[1] = (f32x4){0.f,0.f,0.f,0.f};
  #pragma unroll
  for (int e2 = 0; e2 < 2; ++e2) {
    const int h = (e2<<2) + wv;
    #pragma unroll
    for (int ks = 0; ks < 2; ++ks) {
      const int rb2 = (ks<<5) + (lg<<3);
      B64x2 ua, ub;
      ua.v4[0] = *(const short4v*)&krt[(h<<4) + ll][rb2];
      ua.v4[1] = *(const short4v*)&krt[(h<<4) + ll][rb2+4];
      #pragma unroll
      for (int u = 0; u < 8; ++u)       // v columns from xbf (u16 col reads)
        ub.u[u] = xbf[rb2 + u][(h<<4) + ll];
      kvacc[e2] = __builtin_amdgcn_mfma_f32_16x16x32_bf16(ua.v8, ub.v8, kvacc[e2], 0, 0, 0);
    }
  }

  const int slot = blk & (NSLOTS-1);
  { // kv partial atomics: lane holds kv_h[d=(lg*4+r)][e=ll]
    float* kvp = kv_part + ((size_t)b*NSLOTS + slot) * 2048;
    #pragma unroll
    for (int e2 = 0; e2 < 2; ++e2) {
      const int h = (e2<<2) + wv;
      #pragma unroll
      for (int r = 0; r < 4; ++r) {
        const int d = (lg<<2) + r;
        atomicAdd(&kvp[(h<<8) + (d<<4) + ll], kvacc[e2][r]);
      }
    }
  }
  if (tid < NC) atomicAdd(&ksum_part[((size_t)b*NSLOTS + slot)*NC + tid], ksum_lds[tid]);
}

// ---------------------------------------------------------------------------
// Kred: reduce slots -> kv (scaled 1/n) and kmean
// ---------------------------------------------------------------------------
__global__ __launch_bounds__(256) void k_reduce(
    const float* __restrict__ kv_part, const float* __restrict__ ksum_part,
    float* __restrict__ kvf, float* __restrict__ kmean)
{
  const int gtid = blockIdx.x * 256 + threadIdx.x;
  const int b = gtid >> 11;
  const int cidx = gtid & 2047;
  float s = 0.f;
  for (int sl = 0; sl < NSLOTS; ++sl)
    s += kv_part[((size_t)b*NSLOTS + sl)*2048 + cidx];
  kvf[(size_t)b*2048 + cidx] = s * (1.f/25600.f);
  if (cidx < NC) {
    float t = 0.f;
    for (int sl = 0; sl < NSLOTS; ++sl)
      t += ksum_part[((size_t)b*NSLOTS + sl)*NC + cidx];
    kmean[(size_t)b*NC + cidx] = t * (1.f/25600.f);
  }
}

// ---------------------------------------------------------------------------
// K2: q-GEMM (W from global) + rope/z + MFMA attn + band LePE + store
// ---------------------------------------------------------------------------
__global__ __launch_bounds__(256) void k2_out(
    const float* __restrict__ x, const ushort* __restrict__ wbf,
    const float* __restrict__ qk_b, const float* __restrict__ kvf,
    const float* __restrict__ kmean, const float* __restrict__ lepe_w,
    const float* __restrict__ lepe_b, const float2* __restrict__ rtab,
    float* __restrict__ outp)
{
  __shared__ __align__(16) ushort xs[64][136];   // GEMM A; z_s aliases after GEMM
  __shared__ __align__(16) ushort q_s[64*136];   // q (then roped q) bf16, swizzled
  __shared__ float km_s[NC];
  float (*z_s)[8] = (float(*)[8])&xs[0][0];      // alias (xs dead after GEMM)

  const int blk  = blockIdx.x;
  const int b    = blk / TPB;
  const int tile = blk - b * TPB;
  const int i0   = tile * TILE_R;
  const int tid  = threadIdx.x;
  const int lane = tid & 63;
  const int wv   = tid >> 6;
  const int lg   = lane >> 4;
  const int ll   = lane & 15;
  const float* xb  = x + (size_t)b*NNN*NC;
  const float* xbt = xb + (size_t)i0*NC;

  if (tid < NC) km_s[tid] = kmean[(size_t)b*NC + tid];

  { // stage xs bf16 tile
    const float4* src = (const float4*)xbt;
    for (int f = tid; f < TILE_R*NC/4; f += 256) {
      float4 v = src[f];
      ushort4 u = make_ushort4(f2bf(v.x), f2bf(v.y), f2bf(v.z), f2bf(v.w));
      *(ushort4*)&xs[f >> 5][(f & 31) << 2] = u;
    }
  }

  // per-lane preloads (in flight through GEMM): kv b-frags + lepe weights
  short8v kvb[2];
  float wl2[2][9], lb2[2];
  #pragma unroll
  for (int hs = 0; hs < 2; ++hs) {
    const int h = wv + (hs<<2);
    B64x2 kb; kb.v8 = (short8v){0,0,0,0,0,0,0,0};
    if (lg < 2) {
      #pragma unroll
      for (int j = 0; j < 8; ++j) {
        const int d = (lg<<3) + j;
        kb.u[j] = f2bf(kvf[(size_t)b*2048 + (h<<8) + (d<<4) + ll]);
      }
    }
    kvb[hs] = kb.v8;
    const int ch = (h<<4) + ll;
    #pragma unroll
    for (int t = 0; t < 9; ++t) wl2[hs][t] = lepe_w[ch*9 + t];
    lb2[hs] = lepe_b[ch];
  }
  __syncthreads();   // xs + km_s ready

  // q-GEMM: all 128 cols, B-frags from global bf16
  {
    f32x4 acc[8];
    #pragma unroll
    for (int t = 0; t < 8; ++t) acc[t] = (f32x4){0.f,0.f,0.f,0.f};
    #pragma unroll
    for (int ks = 0; ks < 4; ++ks) {
      short8v a = *(const short8v*)&xs[(wv<<4) + ll][(ks<<5) + (lg<<3)];
      #pragma unroll
      for (int nt = 0; nt < 8; ++nt) {
        short8v bb = *(const short8v*)(wbf + (size_t)((nt<<4) + ll)*NC + (ks<<5) + (lg<<3));
        acc[nt] = __builtin_amdgcn_mfma_f32_16x16x32_bf16(a, bb, acc[nt], 0, 0, 0);
      }
    }
    const int row0 = (wv<<4) + (lg<<2);
    #pragma unroll
    for (int nt = 0; nt < 8; ++nt) {
      const int cg = (nt<<4) + ll;
      const float bias = qk_b[cg];
      #pragma unroll
      for (int r = 0; r < 4; ++r) {
        const int row = row0 + r;
        const int sw  = (row & 7) << 3;
        q_s[row*136 + (cg ^ sw)] = f2bf(elup1(acc[nt][r] + bias));
      }
    }
  }
  __syncthreads();   // q_s complete; xs dead -> z_s alias live

  // phase B: rope + z; task = (row, head); in-place q_s rewrite (swizzled)
  #pragma unroll
  for (int t2 = 0; t2 < 2; ++t2) {
    const int id  = tid + (t2 << 8);
    const int row = id >> 3;
    const int hd  = id & 7;
    const int s   = row & 7;
    const int c0  = (((hd<<1)    ^ s) << 3);
    const int c1  = ((((hd<<1)|1)^ s) << 3);
    uint4 u0 = *(const uint4*)&q_s[row*136 + c0];
    uint4 u1 = *(const uint4*)&q_s[row*136 + c1];
    float q[16];
    q[0]=bflo(u0.x); q[1]=bfhi(u0.x); q[2]=bflo(u0.y); q[3]=bfhi(u0.y);
    q[4]=bflo(u0.z); q[5]=bfhi(u0.z); q[6]=bflo(u0.w); q[7]=bfhi(u0.w);
    q[8]=bflo(u1.x); q[9]=bfhi(u1.x); q[10]=bflo(u1.y); q[11]=bfhi(u1.y);
    q[12]=bflo(u1.z); q[13]=bfhi(u1.z); q[14]=bflo(u1.w); q[15]=bfhi(u1.w);
    float zp = 0.f;
    #pragma unroll
    for (int j = 0; j < 16; ++j) zp += q[j] * km_s[(hd<<4) + j];
    z_s[row][hd] = 1.f / (zp + 1e-6f);
    const int i = i0 + row;
    const int ww = i - divH(i)*NWW;
    const float2* tp = rtab + ww*64 + (hd<<3);
    uint qpk[8];
    #pragma unroll
    for (int j = 0; j < 8; ++j) {
      float2 cs = tp[j];
      float e = q[2*j]*cs.x - q[2*j+1]*cs.y;
      float o = q[2*j]*cs.y + q[2*j+1]*cs.x;
      qpk[j] = (uint)f2bf(e) | ((uint)f2bf(o) << 16);
    }
    *(uint4*)&q_s[row*136 + c0] = make_uint4(qpk[0],qpk[1],qpk[2],qpk[3]);
    *(uint4*)&q_s[row*136 + c1] = make_uint4(qpk[4],qpk[5],qpk[6],qpk[7]);
  }
  __syncthreads();

  // phase C: MFMA attn (K zero-padded 16->32) + z + band LePE + float4 store
  #pragma unroll
  for (int hs = 0; hs < 2; ++hs) {
    const int h  = wv + (hs<<2);
    const int ch = (h<<4) + ll;
    f32x4 pacc[4];
    #pragma unroll
    for (int mt = 0; mt < 4; ++mt) {
      short8v a = (short8v){0,0,0,0,0,0,0,0};
      if (lg < 2) {
        const int row = (mt<<4) + ll;
        const int cblk = ((h<<1) + lg) ^ (row & 7);
        a = *(const short8v*)&q_s[row*136 + (cblk<<3)];
      }
      pacc[mt] = __builtin_amdgcn_mfma_f32_16x16x32_bf16(
          a, kvb[hs], (f32x4){0.f,0.f,0.f,0.f}, 0, 0, 0);
    }
    const float* wl = wl2[hs];
    const float lb  = lb2[hs];
    const float* xc = xb + ch;
    #pragma unroll
    for (int mt = 0; mt < 4; ++mt) {
      const int lrow = (mt<<4) + (lg<<2);
      const int ib   = i0 + lrow;
      // bands: 6 x {up, mid, down}
      float mu[6], mm[6], md[6];
      #pragma unroll
      for (int j = 0; j < 6; ++j) {
        const int im = ib - 1 + j;
        mu[j] = xc[(size_t)(iclamp(im-160, 0, NNN-1)) * NC];
        mm[j] = xc[(size_t)(iclamp(im,     0, NNN-1)) * NC];
        md[j] = xc[(size_t)(iclamp(im+160, 0, NNN-1)) * NC];
      }
      int hh = divH(ib);
      int ww = ib - hh*NWW;
      float4 ov;
      #pragma unroll
      for (int r = 0; r < 4; ++r) {
        const float zz = z_s[lrow + r][h];
        const float fy0 = hh > 0   ? 1.f : 0.f;
        const float fy2 = hh < 159 ? 1.f : 0.f;
        const float fx0 = ww > 0   ? 1.f : 0.f;
        const float fx2 = ww < 159 ? 1.f : 0.f;
        float lp = lb;
        lp += fy0*(fx0*wl[0]*mu[r] + wl[1]*mu[r+1] + fx2*wl[2]*mu[r+2]);
        lp +=     (fx0*wl[3]*mm[r] + wl[4]*mm[r+1] + fx2*wl[5]*mm[r+2]);
        lp += fy2*(fx0*wl[6]*md[r] + wl[7]*md[r+1] + fx2*wl[8]*md[r+2]);
        (&ov.x)[r] = pacc[mt][r]*zz + lp;
        const int cy = (ww == NWW-1) ? 1 : 0;
        hh += cy;
        ww = cy ? 0 : ww + 1;
      }
      *(float4*)(outp + ((size_t)b*NC + ch)*NNN + ib) = ov;
    }
  }
}

// ---------------------------------------------------------------------------
extern "C" void kernel_launch(void* const* d_in, const int* in_sizes, int n_in,
                              void* d_out, int out_size, void* d_ws, size_t ws_size,
                              hipStream_t stream) {
  const float* x      = (const float*)d_in[0];
  const float* qk_w   = (const float*)d_in[1];
  const float* qk_b   = (const float*)d_in[2];
  const float* lepe_w = (const float*)d_in[3];
  const float* lepe_b = (const float*)d_in[4];
  float* outp = (float*)d_out;

  float* kv_part   = (float*)d_ws;                               // B*NSLOTS*2048
  float* ksum_part = kv_part + (size_t)NB*NSLOTS*2048;           // B*NSLOTS*NC
  float* kvf       = ksum_part + (size_t)NB*NSLOTS*NC;           // B*2048
  float* kmean     = kvf + (size_t)NB*2048;                      // B*NC
  float2* rtab     = (float2*)(kmean + (size_t)NB*NC);           // 160*64
  ushort* wbf      = (ushort*)(rtab + (size_t)NWW*64);           // 256*128 bf16

  (void)hipMemsetAsync(kv_part, 0,
      ((size_t)NB*NSLOTS*2048 + (size_t)NB*NSLOTS*NC) * sizeof(float), stream);

  hipLaunchKernelGGL(wprep, dim3(128), dim3(256), 0, stream, qk_w, wbf);
  hipLaunchKernelGGL(ktable, dim3(40), dim3(256), 0, stream, rtab);
  hipLaunchKernelGGL(k1_proj, dim3(NB*TPB), dim3(256), 0, stream,
                     x, wbf, qk_b, rtab, kv_part, ksum_part);
  hipLaunchKernelGGL(k_reduce, dim3(64), dim3(256), 0, stream,
                     kv_part, ksum_part, kvf, kmean);
  hipLaunchKernelGGL(k2_out, dim3(NB*TPB), dim3(256), 0, stream,
                     x, wbf, qk_b, kvf, kmean, lepe_w, lepe_b, rtab, outp);
}